// Round 4
// baseline (1946.464 us; speedup 1.0000x reference)
//
#include <hip/hip_runtime.h>
#include <hip/hip_bf16.h>
#include <stdint.h>

typedef short bf16x8 __attribute__((ext_vector_type(8)));
typedef float f32x4 __attribute__((ext_vector_type(4)));

#define DI __device__ __forceinline__

DI unsigned short f2bf(float f) {
    return __builtin_bit_cast(unsigned short, __float2bfloat16(f));
}

DI f32x4 mfma16(bf16x8 a, bf16x8 b, f32x4 c) {
    return __builtin_amdgcn_mfma_f32_16x16x32_bf16(a, b, c, 0, 0, 0);
}

DI void gload16(const unsigned short* g, unsigned short* l) {
    __builtin_amdgcn_global_load_lds(
        (const __attribute__((address_space(1))) unsigned int*)g,
        (__attribute__((address_space(3))) unsigned int*)l, 16, 0, 0);
}

DI float gelu_f(float hv) {
    float y = 0.7978845608028654f * (hv + 0.044715f * hv * hv * hv);
    float th = 1.0f - 2.0f / (__expf(2.0f * y) + 1.0f);
    return 0.5f * hv * (1.0f + th);
}

// ---------------------------------------------------------------------------
// Prep: f32 weights -> bf16 B-fragment tiles in round order.
// (unchanged from R3 — verified correct)
// ---------------------------------------------------------------------------
__global__ __launch_bounds__(256)
void prep_kernel(const float* __restrict__ qkv_w, const float* __restrict__ proj_w,
                 const float* __restrict__ fc1_w, const float* __restrict__ fc2_w,
                 unsigned short* __restrict__ out)
{
    __shared__ float tileA[256][17];
    __shared__ float tileB[32][129];
    const int tid = threadIdx.x;
    const int tgl = blockIdx.x;           // 0..767
    const int layer = tgl / 192;
    const int tl = tgl % 192;
    bool kindA; const float* W; int ldN = 0, src_n16 = 0, strip = 0, ctb = 0;
    if (tl < 64) {
        int h = tl >> 3, u = tl & 7;
        if (u < 6) { kindA = true;  W = qkv_w + (size_t)layer * 256 * 768; ldN = 768;
                     src_n16 = (u >> 1) * 16 + 2 * h + (u & 1); }
        else       { kindA = false; W = proj_w + (size_t)layer * 256 * 256; ldN = 256;
                     strip = 32 * h; ctb = (u - 6) * 8; }
    } else {
        int q = tl - 64, rp = q >> 2, v = q & 3;
        if (v < 2) { kindA = true;  W = fc1_w + (size_t)layer * 256 * 1024; ldN = 1024;
                     src_n16 = 2 * rp + v; }
        else       { kindA = false; W = fc2_w + (size_t)layer * 1024 * 256; ldN = 256;
                     strip = 32 * rp; ctb = (v - 2) * 8; }
    }
    if (kindA) {
        const int cn = tid & 15, k0 = tid >> 4;
        const float* src = W + src_n16 * 16 + cn;
        #pragma unroll
        for (int p = 0; p < 16; ++p) {
            int kk = p * 16 + k0;
            tileA[kk][cn] = src[(size_t)kk * ldN];
        }
    } else {
        const int kk = tid >> 3, c0 = (tid & 7) * 16;
        const float* src = W + (size_t)(strip + kk) * ldN + ctb * 16 + c0;
        #pragma unroll
        for (int j = 0; j < 16; ++j) tileB[kk][c0 + j] = src[j];
    }
    __syncthreads();
    unsigned short* dst = out + (size_t)tgl * 4096;
    {
        int e0 = tid * 16;
        int s = e0 >> 9;
        int l = (e0 >> 3) & 63;
        union { unsigned short u[8]; bf16x8 v; } pk;
        if (kindA) {
            int kb = 32 * s + 8 * (l >> 4);
            int n = l & 15;
            #pragma unroll
            for (int i = 0; i < 8; ++i) pk.u[i] = f2bf(tileA[kb + i][n]);
        } else {
            int kb = 8 * (l >> 4);
            int cc = s * 16 + (l & 15);
            #pragma unroll
            for (int i = 0; i < 8; ++i) pk.u[i] = f2bf(tileB[kb + i][cc]);
        }
        *(bf16x8*)(dst + e0) = pk.v;
        int e1 = e0 + 8;
        int s1 = e1 >> 9;
        int l1 = (e1 >> 3) & 63;
        union { unsigned short u[8]; bf16x8 v; } pk1;
        if (kindA) {
            int kb = 32 * s1 + 8 * (l1 >> 4);
            int n = l1 & 15;
            #pragma unroll
            for (int i = 0; i < 8; ++i) pk1.u[i] = f2bf(tileA[kb + i][n]);
        } else {
            int kb = 8 * (l1 >> 4);
            int cc = s1 * 16 + (l1 & 15);
            #pragma unroll
            for (int i = 0; i < 8; ++i) pk1.u[i] = f2bf(tileB[kb + i][cc]);
        }
        *(bf16x8*)(dst + e1) = pk1.v;
    }
}

// ---------------------------------------------------------------------------
// Fused kernel: 256 blocks x 512 threads (8 waves), wave owns 2 groups.
// amdgpu_waves_per_eu(2,2): LDS already caps at 1 block/CU = 2 waves/SIMD,
// so pin the RA occupancy target there -> 256-VGPR budget, no spill.
// ---------------------------------------------------------------------------
__global__ __launch_bounds__(512)
__attribute__((amdgpu_waves_per_eu(2, 2)))
void fused_kernel(const float* __restrict__ obs, const int* __restrict__ slide_m,
                  const int* __restrict__ hinge_m, const int* __restrict__ global_m,
                  const int* __restrict__ act_m, const int* __restrict__ morph_m,
                  const int* __restrict__ m_idx, const int* __restrict__ has_g,
                  const float* __restrict__ W_slide, const float* __restrict__ b_slide,
                  const float* __restrict__ W_hinge, const float* __restrict__ b_hinge,
                  const float* __restrict__ W_global, const float* __restrict__ b_global,
                  const float* __restrict__ W_act, const float* __restrict__ pos_emb,
                  const float* __restrict__ ln1_w, const float* __restrict__ ln1_b,
                  const float* __restrict__ qkv_b, const float* __restrict__ proj_b,
                  const float* __restrict__ ln2_w, const float* __restrict__ ln2_b,
                  const float* __restrict__ fc1_b, const float* __restrict__ fc2_b,
                  const float* __restrict__ ls1, const float* __restrict__ ls2,
                  const unsigned short* __restrict__ wsb, float* __restrict__ out)
{
    __shared__ __align__(16) unsigned char smem[149504];
    unsigned short* dbuf = (unsigned short*)smem;            // 32768 B: 2 halves x 2 tiles
    float* ls_lds = (float*)(smem + 32768);                  // 2048 B: ls1[256] + ls2[256]
    const int tid = threadIdx.x;
    const int w = tid >> 6, lane = tid & 63, lq = lane & 15, lg = lane >> 4;
    unsigned char* pw = smem + 34816 + w * 14336;
    unsigned short* slotA = (unsigned short*)pw;             // 4096 B (A-frag transpose)
    unsigned short* qp0 = (unsigned short*)(pw + 4096);      // [16][40]
    unsigned short* k0s = (unsigned short*)(pw + 5376);      // [16][40] (also o/gelu frag)
    unsigned short* vT0 = (unsigned short*)(pw + 6656);      // [32][40]
    unsigned short* qp1 = (unsigned short*)(pw + 9216);
    unsigned short* k1s = (unsigned short*)(pw + 10496);
    unsigned short* vT1 = (unsigned short*)(pw + 11776);

    const int G0 = blockIdx.x * 16 + w * 2;
    const int b = G0 >> 7;
    const int m = m_idx[b];

    // zero pad keys 16..31 of vT (one-time; v-writes only touch cols 0..15)
    #pragma unroll
    for (int ii = 0; ii < 8; ++ii) {
        int idx = ii * 64 + lane;
        int row = idx >> 4, c = idx & 15;
        vT0[row * 40 + 16 + c] = 0;
        vT1[row * 40 + 16 + c] = 0;
    }

    // attention mask bias (same for both groups; per b)
    float bias4[4];
    #pragma unroll
    for (int r = 0; r < 4; ++r)
        bias4[r] = morph_m[b * 256 + lq * 16 + 4 * lg + r] ? 0.0f : -1e9f;

    // ---- embedding into residual registers ----
    f32x4 xr0[16], xr1[16];
    const int hg = has_g[m];
    auto embed = [&](int G, f32x4* xr) {
        #pragma unroll
        for (int r = 0; r < 4; ++r) {
            const int j = lg * 4 + r;
            const size_t tok = (size_t)G * 16 + j;
            const float* ob = obs + tok * 16;
            float o0 = ob[0], o1 = ob[1], o2 = ob[2], o3 = ob[3], o4 = ob[4];
            int sl = slide_m[tok], hi = hinge_m[tok], gl = global_m[tok], am = act_m[tok];
            #pragma unroll
            for (int n = 0; n < 16; ++n) {
                int col = n * 16 + lq;
                float e = 0.f;
                if (sl) {
                    e = o0 * W_slide[col] + o1 * W_slide[256 + col] + b_slide[col];
                } else if (hi) {
                    e = o0 * W_hinge[col] + o1 * W_hinge[256 + col] + o2 * W_hinge[512 + col] + b_hinge[col];
                } else if (gl && hg) {
                    e = b_global[m * 256 + col]
                      + o0 * W_global[(m * 5 + 0) * 256 + col]
                      + o1 * W_global[(m * 5 + 1) * 256 + col]
                      + o2 * W_global[(m * 5 + 2) * 256 + col]
                      + o3 * W_global[(m * 5 + 3) * 256 + col]
                      + o4 * W_global[(m * 5 + 4) * 256 + col];
                }
                if (am) e += W_act[col];
                e += pos_emb[((size_t)m * 16 + j) * 256 + col];
                xr[n][r] = e;
            }
        }
    };
    embed(G0, xr0);
    embed(G0 + 1, xr1);

    auto bfrag = [&](int half, int tt, int s) -> bf16x8 {
        return *(const bf16x8*)(dbuf + half * 8192 + tt * 4096 + s * 512 + lane * 8);
    };
    auto stage2 = [&](int gtile, int half) {
        const unsigned short* src = wsb + (size_t)gtile * 4096 + tid * 8;
        unsigned short* dst = dbuf + half * 8192 + tid * 8;
        gload16(src, dst);
        gload16(src + 4096, dst + 4096);
    };

    bf16x8 av0[8], av1[8];
    auto layer_norm = [&](const float* lw, const float* lb, f32x4* xr, bf16x8* av) {
        float sm[4] = {0, 0, 0, 0}, sq[4] = {0, 0, 0, 0};
        #pragma unroll
        for (int n = 0; n < 16; ++n)
            #pragma unroll
            for (int r = 0; r < 4; ++r) { float v = xr[n][r]; sm[r] += v; sq[r] += v * v; }
        #pragma unroll
        for (int r = 0; r < 4; ++r) {
            #pragma unroll
            for (int mk = 1; mk <= 8; mk <<= 1) {
                sm[r] += __shfl_xor(sm[r], mk, 64);
                sq[r] += __shfl_xor(sq[r], mk, 64);
            }
        }
        float mean[4], rstd[4];
        #pragma unroll
        for (int r = 0; r < 4; ++r) {
            float mu = sm[r] * (1.f / 256.f);
            float var = sq[r] * (1.f / 256.f) - mu * mu;
            mean[r] = mu;
            rstd[r] = rsqrtf(var + 1e-5f);
        }
        #pragma unroll
        for (int half = 0; half < 2; ++half) {
            #pragma unroll
            for (int n8 = 0; n8 < 8; ++n8) {
                int n = half * 8 + n8;
                float wv = lw[n * 16 + lq], bv = lb[n * 16 + lq];
                int s2 = n8 >> 1;
                int t16 = (2 * n + (lq >> 3)) & 3;
                int base = s2 * 512 + (lq & 7);
                #pragma unroll
                for (int r = 0; r < 4; ++r) {
                    float xn = (xr[n][r] - mean[r]) * rstd[r] * wv + bv;
                    slotA[base + (4 * lg + r + 16 * t16) * 8] = f2bf(xn);
                }
            }
            #pragma unroll
            for (int s2 = 0; s2 < 4; ++s2)
                av[half * 4 + s2] = *(const bf16x8*)(slotA + s2 * 512 + lane * 8);
        }
    };

    const float SCALE = 0.17677669529663687f;  // 32^-0.5
    const f32x4 zf = {0.f, 0.f, 0.f, 0.f};

    for (int layer = 0; layer < 4; ++layer) {
        const int TB = layer * 192;
        // refresh ls1/ls2 cache (prev layer's readers are past the last barrier)
        if (tid < 256) ls_lds[tid] = ls1[layer * 256 + tid];
        else           ls_lds[tid] = ls2[layer * 256 + (tid - 256)];

        // ===== LN1 =====
        layer_norm(ln1_w + layer * 256, ln1_b + layer * 256, xr0, av0);
        layer_norm(ln1_w + layer * 256, ln1_b + layer * 256, xr1, av1);

        stage2(TB, 0);
        __syncthreads();

        // pre-add ls1*proj_b (linear fold)
        #pragma unroll
        for (int ct = 0; ct < 16; ++ct) {
            float l1 = ls_lds[ct * 16 + lq];
            float pb = proj_b[layer * 256 + ct * 16 + lq];
            float d = l1 * pb;
            #pragma unroll
            for (int rr = 0; rr < 4; ++rr) { xr0[ct][rr] += d; xr1[ct][rr] += d; }
        }

        // ===== attention phase: 32 rounds (4 per head: q,k,v,proj-strip) =====
        for (int r = 0; r < 32; ++r) {
            if (r + 1 < 32) stage2(TB + (r + 1) * 2, (r + 1) & 1);
            const int half = r & 1;
            const int h = r >> 2, ph = r & 3;
            if (ph < 3) {
                #pragma unroll
                for (int tt = 0; tt < 2; ++tt) {
                    int colq = ph * 256 + (2 * h + tt) * 16 + lq;
                    float bv = qkv_b[layer * 768 + colq];
                    f32x4 a0 = {bv, bv, bv, bv}, a1 = a0;
                    #pragma unroll
                    for (int s = 0; s < 8; ++s) {
                        bf16x8 bf = bfrag(half, tt, s);
                        a0 = mfma16(av0[s], bf, a0);
                        a1 = mfma16(av1[s], bf, a1);
                    }
                    if (ph == 0) {
                        #pragma unroll
                        for (int rr = 0; rr < 4; ++rr) {
                            qp0[(4 * lg + rr) * 40 + tt * 16 + lq] = f2bf(a0[rr]);
                            qp1[(4 * lg + rr) * 40 + tt * 16 + lq] = f2bf(a1[rr]);
                        }
                    } else if (ph == 1) {
                        #pragma unroll
                        for (int rr = 0; rr < 4; ++rr) {
                            k0s[(4 * lg + rr) * 40 + tt * 16 + lq] = f2bf(a0[rr]);
                            k1s[(4 * lg + rr) * 40 + tt * 16 + lq] = f2bf(a1[rr]);
                        }
                    } else {
                        #pragma unroll
                        for (int rr = 0; rr < 4; ++rr) {
                            vT0[(tt * 16 + lq) * 40 + 4 * lg + rr] = f2bf(a0[rr]);
                            vT1[(tt * 16 + lq) * 40 + 4 * lg + rr] = f2bf(a1[rr]);
                        }
                    }
                }
            } else {
                // softmax + PV + o-transpose per group, then flash-proj
                auto attn = [&](unsigned short* qp, unsigned short* ks, unsigned short* vT) -> bf16x8 {
                    bf16x8 kf = *(const bf16x8*)(ks + lq * 40 + lg * 8);
                    bf16x8 qf = *(const bf16x8*)(qp + lq * 40 + lg * 8);
                    f32x4 st = mfma16(kf, qf, zf);     // row=key=4lg+rr, col=query=lq
                    float p[4];
                    float mx = -3e38f;
                    #pragma unroll
                    for (int rr = 0; rr < 4; ++rr) {
                        p[rr] = st[rr] * SCALE + bias4[rr];
                        mx = fmaxf(mx, p[rr]);
                    }
                    mx = fmaxf(mx, __shfl_xor(mx, 16, 64));
                    mx = fmaxf(mx, __shfl_xor(mx, 32, 64));
                    float psum = 0.f;
                    #pragma unroll
                    for (int rr = 0; rr < 4; ++rr) { p[rr] = __expf(p[rr] - mx); psum += p[rr]; }
                    psum += __shfl_xor(psum, 16, 64);
                    psum += __shfl_xor(psum, 32, 64);
                    float inv = 1.f / psum;
                    #pragma unroll
                    for (int rr = 0; rr < 4; ++rr)
                        qp[lq * 40 + lg * 4 + rr] = f2bf(p[rr] * inv);   // P[q=lq][k=4lg+rr]
                    #pragma unroll
                    for (int rr = 0; rr < 4; ++rr)
                        qp[lq * 40 + 16 + lg * 4 + rr] = 0;              // zero keys 16..31
                    bf16x8 pf = *(const bf16x8*)(qp + lq * 40 + lg * 8);
                    f32x4 o0 = mfma16(pf, *(const bf16x8*)(vT + lq * 40 + lg * 8), zf);
                    f32x4 o1 = mfma16(pf, *(const bf16x8*)(vT + (16 + lq) * 40 + lg * 8), zf);
                    // transpose o (16 q x 32 d) into A-frag layout in ks
                    #pragma unroll
                    for (int rr = 0; rr < 4; ++rr) {
                        ks[((4 * lg + rr) + 16 * ((lq >> 3) & 3)) * 8 + (lq & 7)] = f2bf(o0[rr]);
                        ks[((4 * lg + rr) + 16 * ((2 + (lq >> 3)) & 3)) * 8 + (lq & 7)] = f2bf(o1[rr]);
                    }
                    return *(const bf16x8*)(ks + lane * 8);
                };
                bf16x8 of0 = attn(qp0, k0s, vT0);
                bf16x8 of1 = attn(qp1, k1s, vT1);
                #pragma unroll
                for (int ct = 0; ct < 16; ++ct) {
                    bf16x8 bf = bfrag(half, ct >> 3, ct & 7);
                    float l1 = ls_lds[ct * 16 + lq];
                    f32x4 p0 = mfma16(of0, bf, zf);
                    f32x4 p1 = mfma16(of1, bf, zf);
                    #pragma unroll
                    for (int rr = 0; rr < 4; ++rr) {
                        xr0[ct][rr] += l1 * p0[rr];
                        xr1[ct][rr] += l1 * p1[rr];
                    }
                }
            }
            __syncthreads();
        }

        // ===== LN2 + fc2-bias prefold =====
        layer_norm(ln2_w + layer * 256, ln2_b + layer * 256, xr0, av0);
        layer_norm(ln2_w + layer * 256, ln2_b + layer * 256, xr1, av1);
        #pragma unroll
        for (int ct = 0; ct < 16; ++ct) {
            float l2 = ls_lds[256 + ct * 16 + lq];
            float b2 = fc2_b[layer * 256 + ct * 16 + lq];
            float d = l2 * b2;
            #pragma unroll
            for (int rr = 0; rr < 4; ++rr) { xr0[ct][rr] += d; xr1[ct][rr] += d; }
        }

        stage2(TB + 64, 0);
        __syncthreads();

        // ===== MLP phase: 64 rounds (fc1 pair / fc2 strip alternating) =====
        for (int r2 = 0; r2 < 64; ++r2) {
            if (r2 + 1 < 64) stage2(TB + 64 + (r2 + 1) * 2, (r2 + 1) & 1);
            const int half = r2 & 1;
            const int rp = r2 >> 1;
            if ((r2 & 1) == 0) {
                // fc1: 2 tiles -> gelu -> frag transpose
                #pragma unroll
                for (int tt = 0; tt < 2; ++tt) {
                    int colf = (2 * rp + tt) * 16 + lq;
                    float bv = fc1_b[layer * 1024 + colf];
                    f32x4 a0 = {bv, bv, bv, bv}, a1 = a0;
                    #pragma unroll
                    for (int s = 0; s < 8; ++s) {
                        bf16x8 bf = bfrag(half, tt, s);
                        a0 = mfma16(av0[s], bf, a0);
                        a1 = mfma16(av1[s], bf, a1);
                    }
                    int t16 = (2 * tt + (lq >> 3)) & 3;
                    #pragma unroll
                    for (int rr = 0; rr < 4; ++rr) {
                        k0s[((4 * lg + rr) + 16 * t16) * 8 + (lq & 7)] = f2bf(gelu_f(a0[rr]));
                        k1s[((4 * lg + rr) + 16 * t16) * 8 + (lq & 7)] = f2bf(gelu_f(a1[rr]));
                    }
                }
            } else {
                // fc2 strip: fold into residual with ls2
                bf16x8 gf0 = *(const bf16x8*)(k0s + lane * 8);
                bf16x8 gf1 = *(const bf16x8*)(k1s + lane * 8);
                #pragma unroll
                for (int ct = 0; ct < 16; ++ct) {
                    bf16x8 bf = bfrag(half, ct >> 3, ct & 7);
                    float l2 = ls_lds[256 + ct * 16 + lq];
                    f32x4 p0 = mfma16(gf0, bf, zf);
                    f32x4 p1 = mfma16(gf1, bf, zf);
                    #pragma unroll
                    for (int rr = 0; rr < 4; ++rr) {
                        xr0[ct][rr] += l2 * p0[rr];
                        xr1[ct][rr] += l2 * p1[rr];
                    }
                }
            }
            __syncthreads();
        }
    }

    // ---- store ----
    float* op0 = out + (size_t)G0 * 4096;
    float* op1 = op0 + 4096;
    #pragma unroll
    for (int n = 0; n < 16; ++n)
        #pragma unroll
        for (int rr = 0; rr < 4; ++rr) {
            op0[(lg * 4 + rr) * 256 + n * 16 + lq] = xr0[n][rr];
            op1[(lg * 4 + rr) * 256 + n * 16 + lq] = xr1[n][rr];
        }
}

extern "C" void kernel_launch(void* const* d_in, const int* in_sizes, int n_in,
                              void* d_out, int out_size, void* d_ws, size_t ws_size,
                              hipStream_t stream) {
    (void)in_sizes; (void)n_in; (void)out_size; (void)ws_size;
    const float* obs      = (const float*)d_in[0];
    const int*   slide_m  = (const int*)d_in[1];
    const int*   hinge_m  = (const int*)d_in[2];
    const int*   global_m = (const int*)d_in[3];
    const int*   act_m    = (const int*)d_in[4];
    const int*   morph_m  = (const int*)d_in[5];
    const int*   m_idx    = (const int*)d_in[6];
    const int*   has_g    = (const int*)d_in[7];
    const float* W_slide  = (const float*)d_in[8];
    const float* b_slide  = (const float*)d_in[9];
    const float* W_hinge  = (const float*)d_in[10];
    const float* b_hinge  = (const float*)d_in[11];
    const float* W_global = (const float*)d_in[12];
    const float* b_global = (const float*)d_in[13];
    const float* W_act    = (const float*)d_in[14];
    const float* pos_emb  = (const float*)d_in[15];
    const float* ln1_w    = (const float*)d_in[16];
    const float* ln1_b    = (const float*)d_in[17];
    const float* qkv_w    = (const float*)d_in[18];
    const float* qkv_b    = (const float*)d_in[19];
    const float* proj_w   = (const float*)d_in[20];
    const float* proj_b   = (const float*)d_in[21];
    const float* ln2_w    = (const float*)d_in[22];
    const float* ln2_b    = (const float*)d_in[23];
    const float* fc1_w    = (const float*)d_in[24];
    const float* fc1_b    = (const float*)d_in[25];
    const float* fc2_w    = (const float*)d_in[26];
    const float* fc2_b    = (const float*)d_in[27];
    const float* ls1      = (const float*)d_in[28];
    const float* ls2      = (const float*)d_in[29];
    unsigned short* wsb = (unsigned short*)d_ws;

    prep_kernel<<<768, 256, 0, stream>>>(qkv_w, proj_w, fc1_w, fc2_w, wsb);
    fused_kernel<<<256, 512, 0, stream>>>(obs, slide_m, hinge_m, global_m, act_m, morph_m,
        m_idx, has_g, W_slide, b_slide, W_hinge, b_hinge, W_global, b_global, W_act, pos_emb,
        ln1_w, ln1_b, qkv_b, proj_b, ln2_w, ln2_b, fc1_b, fc2_b, ls1, ls2, wsb, (float*)d_out);
}

// Round 5
// 1786.213 us; speedup vs baseline: 1.0897x; 1.0897x over previous
//
#include <hip/hip_runtime.h>
#include <hip/hip_bf16.h>
#include <stdint.h>

typedef short bf16x8 __attribute__((ext_vector_type(8)));
typedef float f32x4 __attribute__((ext_vector_type(4)));

#define DI __device__ __forceinline__

DI unsigned short f2bf(float f) {
    return __builtin_bit_cast(unsigned short, __float2bfloat16(f));
}

DI f32x4 mfma16(bf16x8 a, bf16x8 b, f32x4 c) {
    return __builtin_amdgcn_mfma_f32_16x16x32_bf16(a, b, c, 0, 0, 0);
}

DI void gload16(const unsigned short* g, unsigned short* l) {
    __builtin_amdgcn_global_load_lds(
        (const __attribute__((address_space(1))) unsigned int*)g,
        (__attribute__((address_space(3))) unsigned int*)l, 16, 0, 0);
}

DI float gelu_f(float hv) {
    float y = 0.7978845608028654f * (hv + 0.044715f * hv * hv * hv);
    float th = 1.0f - 2.0f / (__expf(2.0f * y) + 1.0f);
    return 0.5f * hv * (1.0f + th);
}

// ---------------------------------------------------------------------------
// Prep: f32 weights -> bf16 B-fragment tiles in round order.
// (unchanged from R3 — verified correct)
// ---------------------------------------------------------------------------
__global__ __launch_bounds__(256)
void prep_kernel(const float* __restrict__ qkv_w, const float* __restrict__ proj_w,
                 const float* __restrict__ fc1_w, const float* __restrict__ fc2_w,
                 unsigned short* __restrict__ out)
{
    __shared__ float tileA[256][17];
    __shared__ float tileB[32][129];
    const int tid = threadIdx.x;
    const int tgl = blockIdx.x;           // 0..767
    const int layer = tgl / 192;
    const int tl = tgl % 192;
    bool kindA; const float* W; int ldN = 0, src_n16 = 0, strip = 0, ctb = 0;
    if (tl < 64) {
        int h = tl >> 3, u = tl & 7;
        if (u < 6) { kindA = true;  W = qkv_w + (size_t)layer * 256 * 768; ldN = 768;
                     src_n16 = (u >> 1) * 16 + 2 * h + (u & 1); }
        else       { kindA = false; W = proj_w + (size_t)layer * 256 * 256; ldN = 256;
                     strip = 32 * h; ctb = (u - 6) * 8; }
    } else {
        int q = tl - 64, rp = q >> 2, v = q & 3;
        if (v < 2) { kindA = true;  W = fc1_w + (size_t)layer * 256 * 1024; ldN = 1024;
                     src_n16 = 2 * rp + v; }
        else       { kindA = false; W = fc2_w + (size_t)layer * 1024 * 256; ldN = 256;
                     strip = 32 * rp; ctb = (v - 2) * 8; }
    }
    if (kindA) {
        const int cn = tid & 15, k0 = tid >> 4;
        const float* src = W + src_n16 * 16 + cn;
        #pragma unroll
        for (int p = 0; p < 16; ++p) {
            int kk = p * 16 + k0;
            tileA[kk][cn] = src[(size_t)kk * ldN];
        }
    } else {
        const int kk = tid >> 3, c0 = (tid & 7) * 16;
        const float* src = W + (size_t)(strip + kk) * ldN + ctb * 16 + c0;
        #pragma unroll
        for (int j = 0; j < 16; ++j) tileB[kk][c0 + j] = src[j];
    }
    __syncthreads();
    unsigned short* dst = out + (size_t)tgl * 4096;
    {
        int e0 = tid * 16;
        int s = e0 >> 9;
        int l = (e0 >> 3) & 63;
        union { unsigned short u[8]; bf16x8 v; } pk;
        if (kindA) {
            int kb = 32 * s + 8 * (l >> 4);
            int n = l & 15;
            #pragma unroll
            for (int i = 0; i < 8; ++i) pk.u[i] = f2bf(tileA[kb + i][n]);
        } else {
            int kb = 8 * (l >> 4);
            int cc = s * 16 + (l & 15);
            #pragma unroll
            for (int i = 0; i < 8; ++i) pk.u[i] = f2bf(tileB[kb + i][cc]);
        }
        *(bf16x8*)(dst + e0) = pk.v;
        int e1 = e0 + 8;
        int s1 = e1 >> 9;
        int l1 = (e1 >> 3) & 63;
        union { unsigned short u[8]; bf16x8 v; } pk1;
        if (kindA) {
            int kb = 32 * s1 + 8 * (l1 >> 4);
            int n = l1 & 15;
            #pragma unroll
            for (int i = 0; i < 8; ++i) pk1.u[i] = f2bf(tileA[kb + i][n]);
        } else {
            int kb = 8 * (l1 >> 4);
            int cc = s1 * 16 + (l1 & 15);
            #pragma unroll
            for (int i = 0; i < 8; ++i) pk1.u[i] = f2bf(tileB[kb + i][cc]);
        }
        *(bf16x8*)(dst + e1) = pk1.v;
    }
}

// Direct-name macros: private arrays must never be touched through a pointer
// parameter (rule #20 — pointer access defeats SROA, arrays land in scratch).
#define EMBED(G, XR)                                                           \
    do {                                                                       \
        _Pragma("unroll")                                                      \
        for (int r = 0; r < 4; ++r) {                                          \
            const int j = lg * 4 + r;                                          \
            const size_t tok = (size_t)(G) * 16 + j;                           \
            const float* ob = obs + tok * 16;                                  \
            float o0 = ob[0], o1 = ob[1], o2 = ob[2], o3 = ob[3], o4 = ob[4];  \
            int sl = slide_m[tok], hi = hinge_m[tok];                          \
            int gl = global_m[tok], am = act_m[tok];                           \
            _Pragma("unroll")                                                  \
            for (int n = 0; n < 16; ++n) {                                     \
                int col = n * 16 + lq;                                         \
                float e = 0.f;                                                 \
                if (sl) {                                                      \
                    e = o0 * W_slide[col] + o1 * W_slide[256 + col] + b_slide[col]; \
                } else if (hi) {                                               \
                    e = o0 * W_hinge[col] + o1 * W_hinge[256 + col]            \
                      + o2 * W_hinge[512 + col] + b_hinge[col];                \
                } else if (gl && hg) {                                         \
                    e = b_global[m * 256 + col]                                \
                      + o0 * W_global[(m * 5 + 0) * 256 + col]                 \
                      + o1 * W_global[(m * 5 + 1) * 256 + col]                 \
                      + o2 * W_global[(m * 5 + 2) * 256 + col]                 \
                      + o3 * W_global[(m * 5 + 3) * 256 + col]                 \
                      + o4 * W_global[(m * 5 + 4) * 256 + col];                \
                }                                                              \
                if (am) e += W_act[col];                                       \
                e += pos_emb[((size_t)m * 16 + j) * 256 + col];                \
                XR[n][r] = e;                                                  \
            }                                                                  \
        }                                                                      \
    } while (0)

#define LAYER_NORM(LW, LB, XR, AV)                                             \
    do {                                                                       \
        float sm[4] = {0, 0, 0, 0}, sq[4] = {0, 0, 0, 0};                      \
        _Pragma("unroll")                                                      \
        for (int n = 0; n < 16; ++n)                                           \
            _Pragma("unroll")                                                  \
            for (int r = 0; r < 4; ++r) {                                      \
                float v = XR[n][r]; sm[r] += v; sq[r] += v * v;                \
            }                                                                  \
        _Pragma("unroll")                                                      \
        for (int r = 0; r < 4; ++r) {                                          \
            _Pragma("unroll")                                                  \
            for (int mk = 1; mk <= 8; mk <<= 1) {                              \
                sm[r] += __shfl_xor(sm[r], mk, 64);                            \
                sq[r] += __shfl_xor(sq[r], mk, 64);                            \
            }                                                                  \
        }                                                                      \
        float mean[4], rstd[4];                                                \
        _Pragma("unroll")                                                      \
        for (int r = 0; r < 4; ++r) {                                          \
            float mu = sm[r] * (1.f / 256.f);                                  \
            float var = sq[r] * (1.f / 256.f) - mu * mu;                       \
            mean[r] = mu;                                                      \
            rstd[r] = rsqrtf(var + 1e-5f);                                     \
        }                                                                      \
        _Pragma("unroll")                                                      \
        for (int hlf = 0; hlf < 2; ++hlf) {                                    \
            _Pragma("unroll")                                                  \
            for (int n8 = 0; n8 < 8; ++n8) {                                   \
                int n = hlf * 8 + n8;                                          \
                float wv = (LW)[n * 16 + lq], bv = (LB)[n * 16 + lq];          \
                int s2 = n8 >> 1;                                              \
                int t16 = (2 * n + (lq >> 3)) & 3;                             \
                int base = s2 * 512 + (lq & 7);                                \
                _Pragma("unroll")                                              \
                for (int r = 0; r < 4; ++r) {                                  \
                    float xn = (XR[n][r] - mean[r]) * rstd[r] * wv + bv;       \
                    slotA[base + (4 * lg + r + 16 * t16) * 8] = f2bf(xn);      \
                }                                                              \
            }                                                                  \
            _Pragma("unroll")                                                  \
            for (int s2 = 0; s2 < 4; ++s2)                                     \
                AV[hlf * 4 + s2] = *(const bf16x8*)(slotA + s2 * 512 + lane * 8); \
        }                                                                      \
    } while (0)

// ---------------------------------------------------------------------------
// Fused kernel: 256 blocks x 512 threads (8 waves), wave owns 2 groups.
// flat_work_group_size(512,512) + waves_per_eu(2,2): LDS caps at 1 block/CU
// = 2 waves/SIMD, so let the RA use the full 256-VGPR budget.
// ---------------------------------------------------------------------------
__global__
__attribute__((amdgpu_flat_work_group_size(512, 512), amdgpu_waves_per_eu(2, 2)))
void fused_kernel(const float* __restrict__ obs, const int* __restrict__ slide_m,
                  const int* __restrict__ hinge_m, const int* __restrict__ global_m,
                  const int* __restrict__ act_m, const int* __restrict__ morph_m,
                  const int* __restrict__ m_idx, const int* __restrict__ has_g,
                  const float* __restrict__ W_slide, const float* __restrict__ b_slide,
                  const float* __restrict__ W_hinge, const float* __restrict__ b_hinge,
                  const float* __restrict__ W_global, const float* __restrict__ b_global,
                  const float* __restrict__ W_act, const float* __restrict__ pos_emb,
                  const float* __restrict__ ln1_w, const float* __restrict__ ln1_b,
                  const float* __restrict__ qkv_b, const float* __restrict__ proj_b,
                  const float* __restrict__ ln2_w, const float* __restrict__ ln2_b,
                  const float* __restrict__ fc1_b, const float* __restrict__ fc2_b,
                  const float* __restrict__ ls1, const float* __restrict__ ls2,
                  const unsigned short* __restrict__ wsb, float* __restrict__ out)
{
    __shared__ __align__(16) unsigned char smem[149504];
    unsigned short* dbuf = (unsigned short*)smem;            // 32768 B: 2 halves x 2 tiles
    float* ls_lds = (float*)(smem + 32768);                  // 2048 B: ls1[256] + ls2[256]
    const int tid = threadIdx.x;
    const int w = tid >> 6, lane = tid & 63, lq = lane & 15, lg = lane >> 4;
    unsigned char* pw = smem + 34816 + w * 14336;
    unsigned short* slotA = (unsigned short*)pw;             // 4096 B (A-frag transpose)
    unsigned short* qp0 = (unsigned short*)(pw + 4096);      // [16][40]
    unsigned short* k0s = (unsigned short*)(pw + 5376);      // [16][40] (also o/gelu frag)
    unsigned short* vT0 = (unsigned short*)(pw + 6656);      // [32][40]
    unsigned short* qp1 = (unsigned short*)(pw + 9216);
    unsigned short* k1s = (unsigned short*)(pw + 10496);
    unsigned short* vT1 = (unsigned short*)(pw + 11776);

    const int G0 = blockIdx.x * 16 + w * 2;
    const int b = G0 >> 7;
    const int m = m_idx[b];

    // zero pad keys 16..31 of vT (one-time; v-writes only touch cols 0..15)
    #pragma unroll
    for (int ii = 0; ii < 8; ++ii) {
        int idx = ii * 64 + lane;
        int row = idx >> 4, c = idx & 15;
        vT0[row * 40 + 16 + c] = 0;
        vT1[row * 40 + 16 + c] = 0;
    }

    // attention mask bias (same for both groups; per b)
    float bias4[4];
    #pragma unroll
    for (int r = 0; r < 4; ++r)
        bias4[r] = morph_m[b * 256 + lq * 16 + 4 * lg + r] ? 0.0f : -1e9f;

    // ---- embedding into residual registers (direct-name access only) ----
    float xr0[16][4], xr1[16][4];
    const int hg = has_g[m];
    EMBED(G0, xr0);
    EMBED(G0 + 1, xr1);

    auto bfrag = [&](int half, int tt, int s) -> bf16x8 {
        return *(const bf16x8*)(dbuf + half * 8192 + tt * 4096 + s * 512 + lane * 8);
    };
    auto stage2 = [&](int gtile, int half) {
        const unsigned short* src = wsb + (size_t)gtile * 4096 + tid * 8;
        unsigned short* dst = dbuf + half * 8192 + tid * 8;
        gload16(src, dst);
        gload16(src + 4096, dst + 4096);
    };

    bf16x8 av0[8], av1[8];

    const float SCALE = 0.17677669529663687f;  // 32^-0.5
    const f32x4 zf = {0.f, 0.f, 0.f, 0.f};

    for (int layer = 0; layer < 4; ++layer) {
        const int TB = layer * 192;
        // refresh ls1/ls2 cache (prev layer's readers are past the last barrier)
        if (tid < 256) ls_lds[tid] = ls1[layer * 256 + tid];
        else           ls_lds[tid] = ls2[layer * 256 + (tid - 256)];

        // ===== LN1 =====
        LAYER_NORM(ln1_w + layer * 256, ln1_b + layer * 256, xr0, av0);
        LAYER_NORM(ln1_w + layer * 256, ln1_b + layer * 256, xr1, av1);

        stage2(TB, 0);
        __syncthreads();

        // pre-add ls1*proj_b (linear fold)
        #pragma unroll
        for (int ct = 0; ct < 16; ++ct) {
            float l1 = ls_lds[ct * 16 + lq];
            float pb = proj_b[layer * 256 + ct * 16 + lq];
            float d = l1 * pb;
            #pragma unroll
            for (int rr = 0; rr < 4; ++rr) { xr0[ct][rr] += d; xr1[ct][rr] += d; }
        }

        // ===== attention phase: 32 rounds (4 per head: q,k,v,proj-strip) =====
        for (int r = 0; r < 32; ++r) {
            if (r + 1 < 32) stage2(TB + (r + 1) * 2, (r + 1) & 1);
            const int half = r & 1;
            const int h = r >> 2, ph = r & 3;
            if (ph < 3) {
                #pragma unroll
                for (int tt = 0; tt < 2; ++tt) {
                    int colq = ph * 256 + (2 * h + tt) * 16 + lq;
                    float bv = qkv_b[layer * 768 + colq];
                    f32x4 a0 = {bv, bv, bv, bv}, a1 = a0;
                    #pragma unroll
                    for (int s = 0; s < 8; ++s) {
                        bf16x8 bf = bfrag(half, tt, s);
                        a0 = mfma16(av0[s], bf, a0);
                        a1 = mfma16(av1[s], bf, a1);
                    }
                    if (ph == 0) {
                        #pragma unroll
                        for (int rr = 0; rr < 4; ++rr) {
                            qp0[(4 * lg + rr) * 40 + tt * 16 + lq] = f2bf(a0[rr]);
                            qp1[(4 * lg + rr) * 40 + tt * 16 + lq] = f2bf(a1[rr]);
                        }
                    } else if (ph == 1) {
                        #pragma unroll
                        for (int rr = 0; rr < 4; ++rr) {
                            k0s[(4 * lg + rr) * 40 + tt * 16 + lq] = f2bf(a0[rr]);
                            k1s[(4 * lg + rr) * 40 + tt * 16 + lq] = f2bf(a1[rr]);
                        }
                    } else {
                        #pragma unroll
                        for (int rr = 0; rr < 4; ++rr) {
                            vT0[(tt * 16 + lq) * 40 + 4 * lg + rr] = f2bf(a0[rr]);
                            vT1[(tt * 16 + lq) * 40 + 4 * lg + rr] = f2bf(a1[rr]);
                        }
                    }
                }
            } else {
                // softmax + PV + o-transpose per group, then flash-proj
                auto attn = [&](unsigned short* qp, unsigned short* ks, unsigned short* vT) -> bf16x8 {
                    bf16x8 kf = *(const bf16x8*)(ks + lq * 40 + lg * 8);
                    bf16x8 qf = *(const bf16x8*)(qp + lq * 40 + lg * 8);
                    f32x4 st = mfma16(kf, qf, zf);     // row=key=4lg+rr, col=query=lq
                    float p[4];
                    float mx = -3e38f;
                    #pragma unroll
                    for (int rr = 0; rr < 4; ++rr) {
                        p[rr] = st[rr] * SCALE + bias4[rr];
                        mx = fmaxf(mx, p[rr]);
                    }
                    mx = fmaxf(mx, __shfl_xor(mx, 16, 64));
                    mx = fmaxf(mx, __shfl_xor(mx, 32, 64));
                    float psum = 0.f;
                    #pragma unroll
                    for (int rr = 0; rr < 4; ++rr) { p[rr] = __expf(p[rr] - mx); psum += p[rr]; }
                    psum += __shfl_xor(psum, 16, 64);
                    psum += __shfl_xor(psum, 32, 64);
                    float inv = 1.f / psum;
                    #pragma unroll
                    for (int rr = 0; rr < 4; ++rr)
                        qp[lq * 40 + lg * 4 + rr] = f2bf(p[rr] * inv);   // P[q=lq][k=4lg+rr]
                    #pragma unroll
                    for (int rr = 0; rr < 4; ++rr)
                        qp[lq * 40 + 16 + lg * 4 + rr] = 0;              // zero keys 16..31
                    bf16x8 pf = *(const bf16x8*)(qp + lq * 40 + lg * 8);
                    f32x4 o0 = mfma16(pf, *(const bf16x8*)(vT + lq * 40 + lg * 8), zf);
                    f32x4 o1 = mfma16(pf, *(const bf16x8*)(vT + (16 + lq) * 40 + lg * 8), zf);
                    // transpose o (16 q x 32 d) into A-frag layout in ks
                    #pragma unroll
                    for (int rr = 0; rr < 4; ++rr) {
                        ks[((4 * lg + rr) + 16 * ((lq >> 3) & 3)) * 8 + (lq & 7)] = f2bf(o0[rr]);
                        ks[((4 * lg + rr) + 16 * ((2 + (lq >> 3)) & 3)) * 8 + (lq & 7)] = f2bf(o1[rr]);
                    }
                    return *(const bf16x8*)(ks + lane * 8);
                };
                bf16x8 of0 = attn(qp0, k0s, vT0);
                bf16x8 of1 = attn(qp1, k1s, vT1);
                #pragma unroll
                for (int ct = 0; ct < 16; ++ct) {
                    bf16x8 bf = bfrag(half, ct >> 3, ct & 7);
                    float l1 = ls_lds[ct * 16 + lq];
                    f32x4 p0 = mfma16(of0, bf, zf);
                    f32x4 p1 = mfma16(of1, bf, zf);
                    #pragma unroll
                    for (int rr = 0; rr < 4; ++rr) {
                        xr0[ct][rr] += l1 * p0[rr];
                        xr1[ct][rr] += l1 * p1[rr];
                    }
                }
            }
            __syncthreads();
        }

        // ===== LN2 + fc2-bias prefold =====
        LAYER_NORM(ln2_w + layer * 256, ln2_b + layer * 256, xr0, av0);
        LAYER_NORM(ln2_w + layer * 256, ln2_b + layer * 256, xr1, av1);
        #pragma unroll
        for (int ct = 0; ct < 16; ++ct) {
            float l2 = ls_lds[256 + ct * 16 + lq];
            float b2 = fc2_b[layer * 256 + ct * 16 + lq];
            float d = l2 * b2;
            #pragma unroll
            for (int rr = 0; rr < 4; ++rr) { xr0[ct][rr] += d; xr1[ct][rr] += d; }
        }

        stage2(TB + 64, 0);
        __syncthreads();

        // ===== MLP phase: 64 rounds (fc1 pair / fc2 strip alternating) =====
        for (int r2 = 0; r2 < 64; ++r2) {
            if (r2 + 1 < 64) stage2(TB + 64 + (r2 + 1) * 2, (r2 + 1) & 1);
            const int half = r2 & 1;
            const int rp = r2 >> 1;
            if ((r2 & 1) == 0) {
                // fc1: 2 tiles -> gelu -> frag transpose
                #pragma unroll
                for (int tt = 0; tt < 2; ++tt) {
                    int colf = (2 * rp + tt) * 16 + lq;
                    float bv = fc1_b[layer * 1024 + colf];
                    f32x4 a0 = {bv, bv, bv, bv}, a1 = a0;
                    #pragma unroll
                    for (int s = 0; s < 8; ++s) {
                        bf16x8 bf = bfrag(half, tt, s);
                        a0 = mfma16(av0[s], bf, a0);
                        a1 = mfma16(av1[s], bf, a1);
                    }
                    int t16 = (2 * tt + (lq >> 3)) & 3;
                    #pragma unroll
                    for (int rr = 0; rr < 4; ++rr) {
                        k0s[((4 * lg + rr) + 16 * t16) * 8 + (lq & 7)] = f2bf(gelu_f(a0[rr]));
                        k1s[((4 * lg + rr) + 16 * t16) * 8 + (lq & 7)] = f2bf(gelu_f(a1[rr]));
                    }
                }
            } else {
                // fc2 strip: fold into residual with ls2
                bf16x8 gf0 = *(const bf16x8*)(k0s + lane * 8);
                bf16x8 gf1 = *(const bf16x8*)(k1s + lane * 8);
                #pragma unroll
                for (int ct = 0; ct < 16; ++ct) {
                    bf16x8 bf = bfrag(half, ct >> 3, ct & 7);
                    float l2 = ls_lds[256 + ct * 16 + lq];
                    f32x4 p0 = mfma16(gf0, bf, zf);
                    f32x4 p1 = mfma16(gf1, bf, zf);
                    #pragma unroll
                    for (int rr = 0; rr < 4; ++rr) {
                        xr0[ct][rr] += l2 * p0[rr];
                        xr1[ct][rr] += l2 * p1[rr];
                    }
                }
            }
            __syncthreads();
        }
    }

    // ---- store ----
    float* op0 = out + (size_t)G0 * 4096;
    float* op1 = op0 + 4096;
    #pragma unroll
    for (int n = 0; n < 16; ++n)
        #pragma unroll
        for (int rr = 0; rr < 4; ++rr) {
            op0[(lg * 4 + rr) * 256 + n * 16 + lq] = xr0[n][rr];
            op1[(lg * 4 + rr) * 256 + n * 16 + lq] = xr1[n][rr];
        }
}

extern "C" void kernel_launch(void* const* d_in, const int* in_sizes, int n_in,
                              void* d_out, int out_size, void* d_ws, size_t ws_size,
                              hipStream_t stream) {
    (void)in_sizes; (void)n_in; (void)out_size; (void)ws_size;
    const float* obs      = (const float*)d_in[0];
    const int*   slide_m  = (const int*)d_in[1];
    const int*   hinge_m  = (const int*)d_in[2];
    const int*   global_m = (const int*)d_in[3];
    const int*   act_m    = (const int*)d_in[4];
    const int*   morph_m  = (const int*)d_in[5];
    const int*   m_idx    = (const int*)d_in[6];
    const int*   has_g    = (const int*)d_in[7];
    const float* W_slide  = (const float*)d_in[8];
    const float* b_slide  = (const float*)d_in[9];
    const float* W_hinge  = (const float*)d_in[10];
    const float* b_hinge  = (const float*)d_in[11];
    const float* W_global = (const float*)d_in[12];
    const float* b_global = (const float*)d_in[13];
    const float* W_act    = (const float*)d_in[14];
    const float* pos_emb  = (const float*)d_in[15];
    const float* ln1_w    = (const float*)d_in[16];
    const float* ln1_b    = (const float*)d_in[17];
    const float* qkv_w    = (const float*)d_in[18];
    const float* qkv_b    = (const float*)d_in[19];
    const float* proj_w   = (const float*)d_in[20];
    const float* proj_b   = (const float*)d_in[21];
    const float* ln2_w    = (const float*)d_in[22];
    const float* ln2_b    = (const float*)d_in[23];
    const float* fc1_w    = (const float*)d_in[24];
    const float* fc1_b    = (const float*)d_in[25];
    const float* fc2_w    = (const float*)d_in[26];
    const float* fc2_b    = (const float*)d_in[27];
    const float* ls1      = (const float*)d_in[28];
    const float* ls2      = (const float*)d_in[29];
    unsigned short* wsb = (unsigned short*)d_ws;

    prep_kernel<<<768, 256, 0, stream>>>(qkv_w, proj_w, fc1_w, fc2_w, wsb);
    fused_kernel<<<256, 512, 0, stream>>>(obs, slide_m, hinge_m, global_m, act_m, morph_m,
        m_idx, has_g, W_slide, b_slide, W_hinge, b_hinge, W_global, b_global, W_act, pos_emb,
        ln1_w, ln1_b, qkv_b, proj_b, ln2_w, ln2_b, fc1_b, fc2_b, ls1, ls2, wsb, (float*)d_out);
}